// Round 4
// baseline (512.204 us; speedup 1.0000x reference)
//
#include <hip/hip_runtime.h>
#include <math.h>

#define NA 16
#define NS 64
#define NB 100
#define NE 12
#define ML 20
#define DD 512
#define NC (NA*NE)   /* 192 */
#define NR (NA*NS)   /* 1024 */
#define EPSF 1e-5f
#define DELTA_F 0.2f
#define IOU_TOTAL (NA*NS*NB*ML)
#define IOU_BLOCKS ((IOU_TOTAL + 255)/256)   /* 8000 */
#define PIT 34       /* even pitch: 8B-aligned ds_read_b64; conflict-free b64 reads */
#define MID_BLOCKS (NA*(NE+1))               /* 208 */

// ---------- helpers ----------
__device__ inline void wave_minmax64(float v, float& mn, float& mx){
  mn = v; mx = v;
  #pragma unroll
  for (int off = 32; off > 0; off >>= 1){
    mn = fminf(mn, __shfl_xor(mn, off));
    mx = fmaxf(mx, __shfl_xor(mx, off));
  }
}

__device__ inline float block_sum256(float v, float* sred){
  int t = threadIdx.x;
  #pragma unroll
  for (int off = 32; off > 0; off >>= 1) v += __shfl_xor(v, off);
  if ((t & 63) == 0) sred[t >> 6] = v;
  __syncthreads();
  float tot = sred[0] + sred[1] + sred[2] + sred[3];
  __syncthreads();
  return tot;
}

// ---------- gemm pass ----------
// PREF=true: T14 async-stage split — regs staged for slice k0+1 are issued right after
// the post-write barrier, so HBM latency hides under the 16 kk-pair compute phase.
// fmaf chain per accumulator is identical to previous rounds -> bit-identical outputs.
template<int JC, bool PREF>
__device__ __forceinline__ void gemm_pass(
    const float* __restrict__ abase, const float* __restrict__ word,
    const int* __restrict__ scols, float* __restrict__ As, float* __restrict__ Bs,
    int t, int tc, int tb)
{
  float acc[7][JC];
  #pragma unroll
  for (int j = 0; j < 7; ++j)
    #pragma unroll
    for (int jc = 0; jc < JC; ++jc) acc[j][jc] = 0.f;

  if (PREF){
    constexpr int NB4 = JC * 128;            // B float4 count per k0-slice
    constexpr int BS  = (NB4 + 255) / 256;   // B slots per thread (<=3 for JC<=6)
    const int b0 = t >> 3, q = t & 7;        // slot j -> row/col b0+32j, floats q*4..q*4+3
    const bool a3 = (b0 + 96) < NB;          // 4th A slot only for t < 32
    const float* ap[4];
    #pragma unroll
    for (int j = 0; j < 3; ++j) ap[j] = abase + (size_t)(b0 + 32*j) * DD + q*4;
    ap[3] = a3 ? (abase + (size_t)(b0 + 96) * DD + q*4) : ap[0];
    const float* bp[BS];
    bool bok[BS];
    #pragma unroll
    for (int j = 0; j < BS; ++j){
      int c = b0 + 32*j;
      bok[j] = (c < JC*16);
      bp[j] = word + (size_t)scols[bok[j] ? c : 0] * DD + q*4;
    }
    float4 pA[4], pB[BS];
    // prologue: load slice k0=0 into regs
    #pragma unroll
    for (int j = 0; j < 3; ++j) pA[j] = *(const float4*)(ap[j]);
    if (a3) pA[3] = *(const float4*)(ap[3]);
    #pragma unroll
    for (int j = 0; j < BS; ++j) if (bok[j]) pB[j] = *(const float4*)(bp[j]);

    for (int k0 = 0; k0 < DD; k0 += 32){
      // write staged regs -> LDS (vmcnt auto-waited; loads had a full compute phase)
      #pragma unroll
      for (int j = 0; j < 3; ++j){
        float* d = &As[(b0 + 32*j) * PIT + q*4];
        *(float2*)d       = make_float2(pA[j].x, pA[j].y);
        *(float2*)(d + 2) = make_float2(pA[j].z, pA[j].w);
      }
      if (a3){
        float* d = &As[(b0 + 96) * PIT + q*4];
        *(float2*)d       = make_float2(pA[3].x, pA[3].y);
        *(float2*)(d + 2) = make_float2(pA[3].z, pA[3].w);
      }
      #pragma unroll
      for (int j = 0; j < BS; ++j) if (bok[j]){
        float* d = &Bs[(b0 + 32*j) * PIT + q*4];
        *(float2*)d       = make_float2(pB[j].x, pB[j].y);
        *(float2*)(d + 2) = make_float2(pB[j].z, pB[j].w);
      }
      __syncthreads();
      // issue next slice's loads NOW — they land during the compute below
      if (k0 + 32 < DD){
        #pragma unroll
        for (int j = 0; j < 3; ++j) pA[j] = *(const float4*)(ap[j] + k0 + 32);
        if (a3) pA[3] = *(const float4*)(ap[3] + k0 + 32);
        #pragma unroll
        for (int j = 0; j < BS; ++j) if (bok[j]) pB[j] = *(const float4*)(bp[j] + k0 + 32);
      }
      #pragma unroll 4
      for (int kk = 0; kk < 32; kk += 2){
        float2 breg[JC], areg[7];
        #pragma unroll
        for (int jc = 0; jc < JC; ++jc)
          breg[jc] = *(const float2*)&Bs[(jc * 16 + tc) * PIT + kk];
        #pragma unroll
        for (int j = 0; j < 7; ++j){
          int b = tb * 7 + j; b = (b < NB) ? b : (NB - 1);
          areg[j] = *(const float2*)&As[b * PIT + kk];
        }
        #pragma unroll
        for (int j = 0; j < 7; ++j)
          #pragma unroll
          for (int jc = 0; jc < JC; ++jc){
            float s0 = acc[j][jc];
            s0 = fmaf(areg[j].x, breg[jc].x, s0);
            s0 = fmaf(areg[j].y, breg[jc].y, s0);
            acc[j][jc] = s0;
          }
      }
      __syncthreads();
    }
  } else {
    for (int k0 = 0; k0 < DD; k0 += 32){
      for (int i = t; i < NB * 8; i += 256){
        int b = i >> 3, q = i & 7;
        const float4 v = *(const float4*)(abase + (size_t)b * DD + k0 + q * 4);
        float* d = &As[b * PIT + q * 4];
        *(float2*)d       = make_float2(v.x, v.y);
        *(float2*)(d + 2) = make_float2(v.z, v.w);
      }
      for (int i = t; i < JC * 16 * 8; i += 256){
        int c = i >> 3, q = i & 7;
        const float4 v = *(const float4*)(word + (size_t)scols[c] * DD + k0 + q * 4);
        float* d = &Bs[c * PIT + q * 4];
        *(float2*)d       = make_float2(v.x, v.y);
        *(float2*)(d + 2) = make_float2(v.z, v.w);
      }
      __syncthreads();
      #pragma unroll 4
      for (int kk = 0; kk < 32; kk += 2){
        float2 breg[JC], areg[7];
        #pragma unroll
        for (int jc = 0; jc < JC; ++jc)
          breg[jc] = *(const float2*)&Bs[(jc * 16 + tc) * PIT + kk];
        #pragma unroll
        for (int j = 0; j < 7; ++j){
          int b = tb * 7 + j; b = (b < NB) ? b : (NB - 1);
          areg[j] = *(const float2*)&As[b * PIT + kk];
        }
        #pragma unroll
        for (int j = 0; j < 7; ++j)
          #pragma unroll
          for (int jc = 0; jc < JC; ++jc){
            float s0 = acc[j][jc];
            s0 = fmaf(areg[j].x, breg[jc].x, s0);
            s0 = fmaf(areg[j].y, breg[jc].y, s0);
            acc[j][jc] = s0;
          }
      }
      __syncthreads();
    }
  }

  // per-thread max/argmax over this thread's 7 rows (b ascending -> first-index tie-break)
  #pragma unroll
  for (int jc = 0; jc < JC; ++jc){
    int ci = jc * 16 + tc;
    float best = -3.4e38f; int bi = 0;
    #pragma unroll
    for (int j = 0; j < 7; ++j){
      int b = tb * 7 + j;
      if (b < NB){ float v = acc[j][jc]; if (v > best){ best = v; bi = b; } }
    }
    As[ci * 16 + tb] = best;
    Bs[ci * 16 + tb] = (float)bi;
  }
}

__device__ __forceinline__ void gemm_epilogue(
    const float* __restrict__ As, const float* __restrict__ Bs,
    const int* __restrict__ scols, int base, int ncols, int kcnt,
    float* __restrict__ dsim, float* __restrict__ dind, int r, int t)
{
  __syncthreads();
  if (t < ncols){
    int gi = base + t;
    if (gi < kcnt){
      float best = -3.4e38f; int bi = 0;
      #pragma unroll
      for (int g = 0; g < 16; ++g){       // ascending tb == ascending b -> first-index tie-break
        float v = As[t * 16 + g];
        if (v > best){ best = v; bi = (int)Bs[t * 16 + g]; }
      }
      int c = scols[gi];
      dsim[r * NC + c] = best;
      dind[r * NC + c] = (float)bi;
    }
  }
  __syncthreads();
}

// ---------- K1: fused {active-col GEMM+max/argmax} + {IoU tail blocks} ----------
__global__ __launch_bounds__(256, 4) void k_main(
    const float* __restrict__ vis, const float* __restrict__ word,
    const int* __restrict__ elen, const float* __restrict__ boxes,
    const float* __restrict__ det,
    float* __restrict__ dind, float* __restrict__ dsim, float* __restrict__ dtin,
    float* __restrict__ accums, unsigned int* __restrict__ done)
{
  const int t = threadIdx.x;

  if (blockIdx.x >= NR){
    // ---- IoU path (memory-bound, overlaps with gemm blocks) ----
    int idx = (int)(blockIdx.x - NR) * 256 + t;
    if (idx < IOU_TOTAL){
      int m = idx % ML; int t2 = idx / ML; int b = t2 % NB; int t3 = t2 / NB;
      const float4 A = *(const float4*)(boxes + (size_t)(t3 * NB + b) * 4);
      int a = t3 / NS;
      const float4 B = *(const float4*)(det + (size_t)(a * ML + m) * 4);
      float iw = fminf(A.z, B.z) - fmaxf(A.x, B.x);
      float ih = fminf(A.w, B.w) - fmaxf(A.y, B.y);
      bool pos = (iw > 0.f) && (ih > 0.f);
      float inter = pos ? iw * ih : 0.f;
      float a1 = (A.z - A.x) * (A.w - A.y);
      float a2 = (B.z - B.x) * (B.w - B.y);
      float den = a1 + a2 - inter;
      dtin[idx] = pos ? inter / (den > 0.f ? den : 1.f) : 0.f;
    }
    return;
  }

  // ---- GEMM path ----
  __shared__ float As[NB * PIT];      // 3400 floats; aliased as redv (needs <=2048)
  __shared__ float Bs[128 * PIT];     // 4352 floats; aliased as redi
  __shared__ int   scols[NC];
  __shared__ int   s_el[NA];
  __shared__ int   s_cnt;
  const int r  = blockIdx.x;
  const int tc = t & 15;
  const int tb = t >> 4;

  if (r == 0 && t == 0){ accums[0] = 0.f; accums[1] = 0.f; done[0] = 0u; }

  // per-block parallel active-column list (elen is 64B, L2-hot)
  if (t < NA){ int L = elen[t]; L = L < 0 ? 0 : (L > NE ? NE : L); s_el[t] = L; }
  // masked columns: S_=0 everywhere -> max 0, argmax 0. Pre-fill all, overwrite active.
  if (t < NC){ dsim[r * NC + t] = 0.f; dind[r * NC + t] = 0.f; }
  __syncthreads();
  if (t < NC){
    int aw = t / NE, e = t - aw * NE;
    int base = 0;
    #pragma unroll
    for (int i = 0; i < NA; ++i) base += (i < aw) ? s_el[i] : 0;
    if (e < s_el[aw]) scols[base + e] = t;
  }
  if (t == 0){
    int n = 0;
    #pragma unroll
    for (int i = 0; i < NA; ++i) n += s_el[i];
    s_cnt = n;
  }
  __syncthreads();
  const int kcnt = s_cnt;
  if (t < NC && t >= kcnt) scols[t] = (kcnt > 0) ? scols[kcnt - 1] : 0;  // pad tail
  __syncthreads();

  const int jcnt = (kcnt + 15) >> 4;
  if (jcnt == 0) return;              // uniform: all columns masked, zeros already written
  const float* abase = vis + (size_t)r * NB * DD;

  const int jc1 = (jcnt > 8) ? 8 : jcnt;
  switch (jc1){
    case 1: gemm_pass<1,true >(abase, word, scols, As, Bs, t, tc, tb); break;
    case 2: gemm_pass<2,true >(abase, word, scols, As, Bs, t, tc, tb); break;
    case 3: gemm_pass<3,true >(abase, word, scols, As, Bs, t, tc, tb); break;
    case 4: gemm_pass<4,true >(abase, word, scols, As, Bs, t, tc, tb); break;
    case 5: gemm_pass<5,true >(abase, word, scols, As, Bs, t, tc, tb); break;
    case 6: gemm_pass<6,true >(abase, word, scols, As, Bs, t, tc, tb); break;
    case 7: gemm_pass<7,false>(abase, word, scols, As, Bs, t, tc, tb); break;
    default: gemm_pass<8,false>(abase, word, scols, As, Bs, t, tc, tb); break;
  }
  gemm_epilogue(As, Bs, scols, 0, jc1 * 16, kcnt, dsim, dind, r, t);

  if (jcnt > 8){                      // cold path (needs sum(elen) > 128)
    const int jc2 = jcnt - 8;         // 1..4
    switch (jc2){
      case 1: gemm_pass<1,false>(abase, word, scols + 128, As, Bs, t, tc, tb); break;
      case 2: gemm_pass<2,false>(abase, word, scols + 128, As, Bs, t, tc, tb); break;
      case 3: gemm_pass<3,false>(abase, word, scols + 128, As, Bs, t, tc, tb); break;
      default: gemm_pass<4,false>(abase, word, scols + 128, As, Bs, t, tc, tb); break;
    }
    gemm_epilogue(As, Bs, scols, 128, jc2 * 16, kcnt, dsim, dind, r, t);
  }
}

// ---------- K2: fused {Sf columns} + {vis_loss blocks} + last-block final reduction ----------
__global__ __launch_bounds__(256) void k_mid(
    const float* __restrict__ vis, const float* __restrict__ dind,
    const float* __restrict__ dsim, const int* __restrict__ elen,
    float* __restrict__ sf, float* __restrict__ accums,
    unsigned int* __restrict__ done, float* __restrict__ out)
{
  const int a = blockIdx.x, y = blockIdx.y;
  const int t = threadIdx.x, lane = t & 63, w = t >> 6;
  __shared__ float sred[4];
  __shared__ int   s_mi[NS];
  __shared__ float s_inv[NS];
  __shared__ float s_nw2[NS];
  __shared__ float s_sn[NS];
  __shared__ int   s_last;

  if (y == NE){
    // ---- sf role: column-normalize D_sim over s, fold into Sf. wave w -> aw = w,w+4,w+8,w+12
    for (int aw = w; aw < NA; aw += 4){
      float accv = 0.f;
      for (int e = 0; e < NE; ++e){
        int c = aw * NE + e;
        float v = dsim[(a * NS + lane) * NC + c];
        float mn, mx; wave_minmax64(v, mn, mx);
        accv += v * (v - mn) / (mx - mn + EPSF);
      }
      float dv = fmaxf((float)elen[aw], 1.f);
      sf[(a * NS + lane) * NA + aw] = accv / dv;
    }
  } else {
    const int e = y;
    if (e < elen[a]){
      // ---- gram role: vis_loss via ||sum w||^2 identity; simn computed in-block
      if (w == 0){
        float v = dsim[(a * NS + lane) * NC + (a * NE + e)];
        float mn, mx; wave_minmax64(v, mn, mx);
        s_sn[lane] = (v - mn) / (mx - mn + EPSF);
      }
      if (t < NS) s_mi[t] = (int)dind[(size_t)(a * NS + t) * NC + (a * NE + e)];
      __syncthreads();

      // phase 1: all 64 row norms, wave-parallel
      for (int s = w; s < NS; s += 4){
        const float* row = vis + (size_t)((a * NS + s) * NB + s_mi[s]) * DD;
        float4 v0 = *(const float4*)(row + lane * 8);
        float4 v1 = *(const float4*)(row + lane * 8 + 4);
        float ss = v0.x*v0.x + v0.y*v0.y + v0.z*v0.z + v0.w*v0.w
                 + v1.x*v1.x + v1.y*v1.y + v1.z*v1.z + v1.w*v1.w;
        #pragma unroll
        for (int off = 32; off > 0; off >>= 1) ss += __shfl_xor(ss, off);
        if (lane == 0){
          float sn = s_sn[s];
          float d = sqrtf(ss) + EPSF;
          s_inv[s] = sn / d;
          s_nw2[s] = sn * sn * ss / (d * d);
        }
      }
      __syncthreads();

      // phase 2: W = sum_s inv_s * row_s (s-ascending chain preserved; rows L2-hot)
      float W0 = 0.f, W1 = 0.f;
      #pragma unroll 8
      for (int s = 0; s < NS; ++s){
        const float* row = vis + (size_t)((a * NS + s) * NB + s_mi[s]) * DD;
        float inv = s_inv[s];
        W0 = fmaf(row[t],       inv, W0);
        W1 = fmaf(row[t + 256], inv, W1);
      }
      float w2  = block_sum256(W0 * W0 + W1 * W1, sred);
      float nw2 = block_sum256((t < NS) ? s_nw2[t] : 0.f, sred);
      if (t == 0){
        float part = (float)(NS * (NS - 1)) - w2 + nw2;
        atomicAdd(&accums[0], part);
        atomicAdd(&accums[1], (float)(NS * (NS - 1)));
      }
    }
  }

  // ---- completion: last finishing block runs the final reduction ----
  __syncthreads();
  if (t == 0){
    __threadfence();
    unsigned int old = atomicAdd(done, 1u);
    s_last = (old == (unsigned int)(MID_BLOCKS - 1)) ? 1 : 0;
  }
  __syncthreads();
  if (s_last){
    __threadfence();
    float sum = 0.f;
    for (int i = t; i < NA * NS * NA; i += 256){
      int b = i & (NA - 1);
      int a2 = i >> 10;
      int s2 = (i >> 4) & (NS - 1);
      float v  = sf[i];
      float d1 = sf[(b * NS + s2) * NA + b];
      float d2 = sf[(a2 * NS + s2) * NA + a2];
      sum += fmaxf(v - d1 + DELTA_F, 0.f) + fmaxf(v - d2 + DELTA_F, 0.f);
    }
    float tot = block_sum256(sum, sred);
    if (t == 0){
      float frame = tot / (float)(NA * NA * NS);
      float cnt = accums[1];
      float vis_loss = accums[0] / fmaxf(cnt, 1.f);
      out[0] = (frame + vis_loss) * 10.f;
    }
  }
}

// ---------- launch ----------
extern "C" void kernel_launch(void* const* d_in, const int* in_sizes, int n_in,
                              void* d_out, int out_size, void* d_ws, size_t ws_size,
                              hipStream_t stream)
{
  const float* vis   = (const float*)d_in[0];
  const float* word  = (const float*)d_in[1];
  const float* boxes = (const float*)d_in[2];
  const float* det   = (const float*)d_in[3];
  const int*   elen  = (const int*)d_in[4];

  float* out   = (float*)d_out;
  float* dind  = out;                       // 196608 (indices as float)
  float* dsim  = out + NR * NC;             // 196608
  float* mloss = out + 2 * NR * NC;         // 1
  float* dtin  = mloss + 1;                 // 2,048,000

  float* ws     = (float*)d_ws;
  float* sf     = ws;                       // 16*64*16 = 16384
  float* accums = ws + NA * NS * NA;        // 2 floats
  unsigned int* done = (unsigned int*)(accums + 2);

  k_main<<<NR + IOU_BLOCKS, 256, 0, stream>>>(vis, word, elen, boxes, det,
                                              dind, dsim, dtin, accums, done);
  k_mid<<<dim3(NA, NE + 1), 256, 0, stream>>>(vis, dind, dsim, elen,
                                              sf, accums, done, mloss);
}